// Round 9
// baseline (182.913 us; speedup 1.0000x reference)
//
#include <hip/hip_runtime.h>
#include <hip/hip_bf16.h>

#define N_NODES 4096
#define N_EDGES 8192
#define N_GRAPHS 64
#define HDIM 128

typedef __attribute__((ext_vector_type(8))) short bf16x8;
typedef __attribute__((ext_vector_type(4))) float f32x4;
typedef __attribute__((ext_vector_type(4))) unsigned short u16x4;

static __device__ __forceinline__ unsigned short f2bf(float f) {
    unsigned u = __builtin_bit_cast(unsigned, f);
    u += 0x7fffu + ((u >> 16) & 1u);
    return (unsigned short)(u >> 16);
}
static __device__ __forceinline__ float bf2f(unsigned short s) {
    unsigned u = ((unsigned)s) << 16;
    return __builtin_bit_cast(float, u);
}

// ---------------- pre: node MLP (+hb bias path), weight packs (w4,w2,w3), edge l1.
// grid 452: [0,256) node MLP, [256,384) w4 pack, {384,385} w2 pack, {386,387} w3 pack,
//           [388,452) edge l1 (128 edges/block) -> l1bf global bf16 [8192][128]
__global__ __launch_bounds__(256) void pre_kernel(
    const float* __restrict__ x, const float* __restrict__ p1w, const float* __restrict__ p1b,
    const float* __restrict__ p2w, const float* __restrict__ p2b, const float* __restrict__ e4b,
    unsigned short* __restrict__ h_bf, float* __restrict__ hb,
    const float* __restrict__ ea, const float* __restrict__ w1, const float* __restrict__ b1,
    const float* __restrict__ w4, unsigned short* __restrict__ w4perm,
    const float* __restrict__ w2, unsigned short* __restrict__ w2p,
    const float* __restrict__ w3, unsigned short* __restrict__ w3p,
    unsigned short* __restrict__ l1bf)
{
    __shared__ __align__(16) char smem[33024];
    const int t = threadIdx.x;
    const int bid = blockIdx.x;

    if (bid < 256) {
        // ---- node MLP: h = relu(x@p1+b1)@p2+b2 ; hb = h @ B4
        float (*xs)[11]  = (float(*)[11])smem;           // 704 B
        float (*l1t)[16] = (float(*)[16])(smem + 704);   // 8192 B
        float (*hs)[16]  = (float(*)[16])(smem + 8896);  // 8192 B
        const int nb = bid;

        for (int r = t; r < 16 * 11; r += 256) {
            int e = r / 11, d = r % 11;
            xs[e][d] = x[(nb * 16 + e) * 11 + d];
        }
        __syncthreads();
        {
            int j = t & 127;
            float wd[11];
            #pragma unroll
            for (int d = 0; d < 11; ++d) wd[d] = p1w[d * 128 + j];
            float bj = p1b[j];
            for (int p = 0; p < 8; ++p) {
                int e = p * 2 + (t >> 7);
                float acc = bj;
                #pragma unroll
                for (int d = 0; d < 11; ++d) acc += xs[e][d] * wd[d];
                l1t[j][e] = fmaxf(acc, 0.f);
            }
        }
        __syncthreads();
        {
            int j = t & 127, eh = t >> 7;
            float acc[8];
            float bj = p2b[j];
            #pragma unroll
            for (int r = 0; r < 8; ++r) acc[r] = bj;
            for (int k = 0; k < 128; ++k) {
                float w = p2w[k * 128 + j];
                const float4* row = (const float4*)&l1t[k][eh * 8];
                float4 v0 = row[0], v1 = row[1];
                acc[0] += v0.x * w; acc[1] += v0.y * w; acc[2] += v0.z * w; acc[3] += v0.w * w;
                acc[4] += v1.x * w; acc[5] += v1.y * w; acc[6] += v1.z * w; acc[7] += v1.w * w;
            }
            #pragma unroll
            for (int r = 0; r < 8; ++r) {
                int e = eh * 8 + r;
                h_bf[(nb * 16 + e) * 128 + j] = f2bf(acc[r]);
                hs[j][e] = acc[r];
            }
        }
        __syncthreads();
        {
            int j = t & 127, eh = t >> 7;
            float acc[8] = {0.f,0.f,0.f,0.f,0.f,0.f,0.f,0.f};
            for (int i = 0; i < 128; ++i) {
                float w = e4b[i * 128 + j];
                const float4* row = (const float4*)&hs[i][eh * 8];
                float4 v0 = row[0], v1 = row[1];
                acc[0] += v0.x * w; acc[1] += v0.y * w; acc[2] += v0.z * w; acc[3] += v0.w * w;
                acc[4] += v1.x * w; acc[5] += v1.y * w; acc[6] += v1.z * w; acc[7] += v1.w * w;
            }
            #pragma unroll
            for (int r = 0; r < 8; ++r) hb[(nb * 16 + eh * 8 + r) * 128 + j] = acc[r];
        }
    } else if (bid < 384) {
        // ---- pack e4_w into bf16 [o>>5:4][chunk i:128][o&31:32][k:136]
        unsigned short (*tt)[129] = (unsigned short(*)[129])smem;  // 33024 B
        const int i = bid - 256;
        for (int r = t; r < 16384; r += 256) {
            int k = r >> 7, o = r & 127;
            tt[o][k] = f2bf(w4[k * 16384 + i * 128 + o]);
        }
        __syncthreads();
        for (int r = t; r < 16384; r += 256) {
            int o = r >> 7, k = r & 127;
            w4perm[((size_t)(o >> 5) * 128 + i) * 4352 + (size_t)(o & 31) * 136 + k] = tt[o][k];
        }
    } else if (bid < 386) {
        // ---- pack w2 (f32 [128 k][256 o]) -> w2p bf16 [o:256][k:136]
        unsigned short (*tt)[129] = (unsigned short(*)[129])smem;  // [128 o][129 k]
        const int oh = bid - 384;
        for (int r = t; r < 16384; r += 256) {
            int k = r >> 7, ol = r & 127;
            tt[ol][k] = f2bf(w2[k * 256 + oh * 128 + ol]);
        }
        __syncthreads();
        for (int r = t; r < 16384; r += 256) {
            int ol = r >> 7, k = r & 127;
            w2p[(oh * 128 + ol) * 136 + k] = tt[ol][k];
        }
    } else if (bid < 388) {
        // ---- pack w3 (f32 [256 k][128 o]) -> w3p bf16 [o:128][k:264]
        unsigned short (*tt)[257] = (unsigned short(*)[257])smem;  // [64 o][257 k]
        const int oh = bid - 386;
        for (int r = t; r < 16384; r += 256) {
            int k = r >> 6, ol = r & 63;
            tt[ol][k] = f2bf(w3[k * 128 + oh * 64 + ol]);
        }
        __syncthreads();
        for (int r = t; r < 16384; r += 256) {
            int ol = r >> 8, k = r & 255;
            w3p[(oh * 64 + ol) * 264 + k] = tt[ol][k];
        }
    } else {
        // ---- edge l1: 5 -> 128 relu -> l1bf bf16 global (128 edges/block, 64 blocks)
        float (*es)[5] = (float(*)[5])smem;   // 128 edges x 5 f32 = 2560 B
        const int eb = (bid - 388) * 128;
        for (int r = t; r < 640; r += 256) ((float*)es)[r] = ea[eb * 5 + r];
        __syncthreads();
        int j = t & 127, eh = t >> 7;
        float wd[5];
        #pragma unroll
        for (int d = 0; d < 5; ++d) wd[d] = w1[d * 128 + j];
        float bj = b1[j];
        for (int p = 0; p < 64; ++p) {
            int e = eh * 64 + p;
            float acc = bj;
            #pragma unroll
            for (int d = 0; d < 5; ++d) acc += es[e][d] * wd[d];
            l1bf[(size_t)(eb + e) * 128 + j] = f2bf(fmaxf(acc, 0.f));
        }
    }
}

// ---------------- edge MLP l2+l3 via MFMA: [8192,128]@[128,256] relu @[256,128] relu.
// 256 blocks x 32 edges. A-frags from global l1bf; B-frags direct from global packed
// w2p/w3p (L2-resident). l2 activations staged in LDS [32][264] bf16.
__global__ __launch_bounds__(256, 2) void edge23_kernel(
    const unsigned short* __restrict__ l1bf,
    const float* __restrict__ b2, const float* __restrict__ b3,
    const unsigned short* __restrict__ w2p, const unsigned short* __restrict__ w3p,
    unsigned short* __restrict__ e3bf)
{
    __shared__ __align__(16) unsigned short l2a[32 * 264];   // 16.9 KB
    const int t = threadIdx.x, bid = blockIdx.x;
    const int w = t >> 6, lane = t & 63, q = lane >> 4, l15 = lane & 15;
    const int e0 = bid * 32;
    const f32x4 zero4 = (f32x4){0.f, 0.f, 0.f, 0.f};

    bf16x8 afrag[2][4];
    #pragma unroll
    for (int mb = 0; mb < 2; ++mb)
        #pragma unroll
        for (int s = 0; s < 4; ++s)
            afrag[mb][s] = *(const bf16x8*)(l1bf + (size_t)(e0 + mb * 16 + l15) * 128 + s * 32 + q * 8);

    f32x4 acc[2][4];
    #pragma unroll
    for (int mb = 0; mb < 2; ++mb)
        #pragma unroll
        for (int ob = 0; ob < 4; ++ob) acc[mb][ob] = zero4;
    #pragma unroll
    for (int ob = 0; ob < 4; ++ob) {
        const int o = w * 64 + ob * 16 + l15;
        bf16x8 bfrag[4];
        #pragma unroll
        for (int s = 0; s < 4; ++s)
            bfrag[s] = *(const bf16x8*)(w2p + (size_t)o * 136 + s * 32 + q * 8);
        #pragma unroll
        for (int mb = 0; mb < 2; ++mb) {
            f32x4 tmp = __builtin_amdgcn_mfma_f32_16x16x32_bf16(afrag[mb][0], bfrag[0], zero4, 0, 0, 0);
            tmp = __builtin_amdgcn_mfma_f32_16x16x32_bf16(afrag[mb][1], bfrag[1], tmp, 0, 0, 0);
            tmp = __builtin_amdgcn_mfma_f32_16x16x32_bf16(afrag[mb][2], bfrag[2], tmp, 0, 0, 0);
            acc[mb][ob] = __builtin_amdgcn_mfma_f32_16x16x32_bf16(afrag[mb][3], bfrag[3], tmp, 0, 0, 0);
        }
    }
    #pragma unroll
    for (int mb = 0; mb < 2; ++mb)
        #pragma unroll
        for (int ob = 0; ob < 4; ++ob) {
            int o = w * 64 + ob * 16 + l15;
            float bo = b2[o];
            #pragma unroll
            for (int r = 0; r < 4; ++r) {
                int e_loc = mb * 16 + q * 4 + r;
                l2a[e_loc * 264 + o] = f2bf(fmaxf(acc[mb][ob][r] + bo, 0.f));
            }
        }
    __syncthreads();

    f32x4 acc3[2][2];
    #pragma unroll
    for (int mb = 0; mb < 2; ++mb)
        #pragma unroll
        for (int ob = 0; ob < 2; ++ob) acc3[mb][ob] = zero4;
    #pragma unroll
    for (int ks = 0; ks < 8; ++ks) {
        bf16x8 a3[2];
        #pragma unroll
        for (int mb = 0; mb < 2; ++mb)
            a3[mb] = *(const bf16x8*)&l2a[(mb * 16 + l15) * 264 + ks * 32 + q * 8];
        #pragma unroll
        for (int ob = 0; ob < 2; ++ob) {
            const int o = w * 32 + ob * 16 + l15;
            bf16x8 bf = *(const bf16x8*)(w3p + (size_t)o * 264 + ks * 32 + q * 8);
            #pragma unroll
            for (int mb = 0; mb < 2; ++mb)
                acc3[mb][ob] = __builtin_amdgcn_mfma_f32_16x16x32_bf16(a3[mb], bf, acc3[mb][ob], 0, 0, 0);
        }
    }
    #pragma unroll
    for (int mb = 0; mb < 2; ++mb)
        #pragma unroll
        for (int ob = 0; ob < 2; ++ob) {
            int o = w * 32 + ob * 16 + l15;
            float bo = b3[o];
            #pragma unroll
            for (int r = 0; r < 4; ++r) {
                int e = e0 + mb * 16 + q * 4 + r;
                e3bf[(size_t)e * 128 + o] = f2bf(fmaxf(acc3[mb][ob][r] + bo, 0.f));
            }
        }
}

// ---------------- fused NNConv message GEMM, v8b: mb=8 edge-tile (128e x 16o x full K).
// Halves B L2-traffic (571->285 MB), halves B-load instrs, halves atomics (ONE atomic
// per (e,o) total = 1.05M). Waves = 4-way K-parallel, LDS-reduced. bid&7 = osplit = XCD
// (one 557 KB 16-o slice per XCD, L2-resident). Manual 1-chunk-ahead B prefetch.
// v8 bug fixed: h-gather loop was u<4 (copied from v4's 64-i geometry) -> ht rows
// 32-63 & 96-127 uninitialized -> NaN. Each thread owns a 64-i half = 8 uint4 loads.
__global__ __launch_bounds__(256, 2) void nnconv_kernel(
    const unsigned short* __restrict__ e3bf, const unsigned short* __restrict__ h_bf,
    const unsigned short* __restrict__ w4perm, const float* __restrict__ hb,
    const int* __restrict__ ei, float* __restrict__ agg, float* __restrict__ cnt)
{
    __shared__ __align__(16) unsigned short ht[128 * 128];  // [i:128][e:128] bf16, 32 KB
    __shared__ __align__(16) float red[3 * 128 * 16];       // [w-1][e_loc][l15] f32, 24 KB
    const int t = threadIdx.x;
    const int bid = blockIdx.x;
    const int osplit = bid & 7;          // 8 o-slices of 16 (== XCD)
    const int etile  = bid >> 3;         // 64 tiles of 128 edges
    const int w = t >> 6, lane = t & 63, q = lane >> 4, l15 = lane & 15;
    const int kpar = w;                  // each wave owns 32 of the 128 chunks
    const int e0 = etile * 128;
    const int o0 = osplit * 16;

    // A fragments: this block's 128 e3 rows (full K=128), constant across all chunks.
    bf16x8 afrag[8][4];
    #pragma unroll
    for (int mb = 0; mb < 8; ++mb)
        #pragma unroll
        for (int s = 0; s < 4; ++s) {
            int row = e0 + mb * 16 + l15;
            afrag[mb][s] = *(const bf16x8*)(e3bf + (size_t)row * 128 + s * 32 + q * 8);
        }
    #pragma unroll
    for (int mb = 0; mb < 8; ++mb)
        #pragma unroll
        for (int s = 0; s < 4; ++s)
            asm volatile("" : "+v"(afrag[mb][s]));
    asm volatile("" ::: "memory");   // forbid rematerializing the e3bf loads

    {   // gather h rows through src[e]: 2 threads/edge, 64 i each = 8 uint4 loads (FIX: u<8)
        int r = t >> 1, part = t & 1;
        int s = ei[e0 + r];
        #pragma unroll
        for (int u = 0; u < 8; ++u) {
            uint4 v = *(const uint4*)(h_bf + (size_t)s * 128 + part * 64 + u * 8);
            const unsigned short* pv = (const unsigned short*)&v;
            #pragma unroll
            for (int j = 0; j < 8; ++j)
                ht[(part * 64 + u * 8 + j) * 128 + r] = pv[j];
        }
    }

    f32x4 acc[8];
    #pragma unroll
    for (int mb = 0; mb < 8; ++mb) acc[mb] = (f32x4){0.f, 0.f, 0.f, 0.f};
    const f32x4 zero4 = (f32x4){0.f, 0.f, 0.f, 0.f};

    __syncthreads();   // ht ready

    // K-loop: 32 chunks per wave, B-frags straight from global (L2-resident slice),
    // software-pipelined one chunk ahead so the L2 latency hides under 32 MFMAs.
    const unsigned short* bbase =
        w4perm + ((size_t)(osplit >> 1) * 128 + kpar * 32) * 4352
               + (size_t)((osplit & 1) * 16 + l15) * 136 + q * 8;
    bf16x8 bcur[4], bnxt[4];
    #pragma unroll
    for (int s = 0; s < 4; ++s) bcur[s] = *(const bf16x8*)(bbase + s * 32);
    for (int c = 0; c < 32; ++c) {
        if (c + 1 < 32) {
            const unsigned short* bp = bbase + (size_t)(c + 1) * 4352;
            #pragma unroll
            for (int s = 0; s < 4; ++s) bnxt[s] = *(const bf16x8*)(bp + s * 32);
        }
        const int gi = kpar * 32 + c;    // global chunk = i-row of ht
        #pragma unroll
        for (int mb = 0; mb < 8; ++mb) {
            u16x4 hr = *(const u16x4*)&ht[gi * 128 + mb * 16 + q * 4];
            f32x4 tmp = __builtin_amdgcn_mfma_f32_16x16x32_bf16(afrag[mb][0], bcur[0], zero4, 0, 0, 0);
            tmp = __builtin_amdgcn_mfma_f32_16x16x32_bf16(afrag[mb][1], bcur[1], tmp, 0, 0, 0);
            tmp = __builtin_amdgcn_mfma_f32_16x16x32_bf16(afrag[mb][2], bcur[2], tmp, 0, 0, 0);
            tmp = __builtin_amdgcn_mfma_f32_16x16x32_bf16(afrag[mb][3], bcur[3], tmp, 0, 0, 0);
            #pragma unroll
            for (int r = 0; r < 4; ++r)
                acc[mb][r] += bf2f(hr[r]) * tmp[r];
        }
        #pragma unroll
        for (int s = 0; s < 4; ++s) bcur[s] = bnxt[s];
    }

    // 4-way kpar reduction through LDS, then ONE atomic per (e,o).
    if (w > 0) {
        #pragma unroll
        for (int mb = 0; mb < 8; ++mb)
            #pragma unroll
            for (int r = 0; r < 4; ++r)
                red[((w - 1) * 128 + mb * 16 + q * 4 + r) * 16 + l15] = acc[mb][r];
    }
    __syncthreads();
    if (w == 0) {
        #pragma unroll
        for (int mb = 0; mb < 8; ++mb) {
            #pragma unroll
            for (int r = 0; r < 4; ++r) {
                int e_loc = mb * 16 + q * 4 + r;
                int e = e0 + e_loc;
                int de = ei[N_EDGES + e];
                int se = ei[e];
                int o = o0 + l15;
                float v = acc[mb][r]
                        + red[(0 * 128 + e_loc) * 16 + l15]
                        + red[(1 * 128 + e_loc) * 16 + l15]
                        + red[(2 * 128 + e_loc) * 16 + l15]
                        + hb[(size_t)se * 128 + o];
                if (osplit == 0 && l15 == 0) atomicAdd(&cnt[de], 1.0f);
                atomicAdd(&agg[(size_t)de * 128 + o], v);
            }
        }
    }
}

// ---------------- scatter-mean finalize + global add pool.
// batch is SORTED -> one block per graph, binary-search bounds, direct store (no atomics).
__global__ __launch_bounds__(128) void pool_kernel(
    const float* __restrict__ agg, const float* __restrict__ cnt,
    const int* __restrict__ batch, float* __restrict__ out)
{
    const int g = blockIdx.x, t = threadIdx.x;  // t = output channel o
    int lo = 0, hi = N_NODES;
    while (lo < hi) { int m = (lo + hi) >> 1; if (batch[m] < g) lo = m + 1; else hi = m; }
    const int n_lo = lo;
    int lo2 = n_lo, hi2 = N_NODES;
    while (lo2 < hi2) { int m = (lo2 + hi2) >> 1; if (batch[m] < g + 1) lo2 = m + 1; else hi2 = m; }
    const int n_hi = lo2;

    float s0 = 0.f, s1 = 0.f, s2 = 0.f, s3 = 0.f;
    int n = n_lo;
    for (; n + 4 <= n_hi; n += 4) {
        float c0 = cnt[n], c1 = cnt[n + 1], c2 = cnt[n + 2], c3 = cnt[n + 3];
        float v0 = agg[(n    ) * 128 + t];
        float v1 = agg[(n + 1) * 128 + t];
        float v2 = agg[(n + 2) * 128 + t];
        float v3 = agg[(n + 3) * 128 + t];
        s0 += v0 / (c0 > 1.f ? c0 : 1.f);
        s1 += v1 / (c1 > 1.f ? c1 : 1.f);
        s2 += v2 / (c2 > 1.f ? c2 : 1.f);
        s3 += v3 / (c3 > 1.f ? c3 : 1.f);
    }
    for (; n < n_hi; ++n) {
        float c = cnt[n];
        s0 += agg[n * 128 + t] / (c > 1.f ? c : 1.f);
    }
    out[g * 128 + t] = (s0 + s1) + (s2 + s3);
}

extern "C" void kernel_launch(void* const* d_in, const int* in_sizes, int n_in,
                              void* d_out, int out_size, void* d_ws, size_t ws_size,
                              hipStream_t stream)
{
    const float* x     = (const float*)d_in[0];
    const float* ea    = (const float*)d_in[1];
    const int*   ei    = (const int*)d_in[2];
    const int*   batch = (const int*)d_in[3];
    const float* p1w   = (const float*)d_in[4];
    const float* p1b   = (const float*)d_in[5];
    const float* p2w   = (const float*)d_in[6];
    const float* p2b   = (const float*)d_in[7];
    const float* w1    = (const float*)d_in[8];
    const float* b1    = (const float*)d_in[9];
    const float* w2    = (const float*)d_in[10];
    const float* b2    = (const float*)d_in[11];
    const float* w3    = (const float*)d_in[12];
    const float* b3    = (const float*)d_in[13];
    const float* w4    = (const float*)d_in[14];
    const float* b4    = (const float*)d_in[15];
    float* out = (float*)d_out;
    (void)in_sizes; (void)n_in; (void)out_size; (void)ws_size;

    char* ws = (char*)d_ws;
    unsigned short* h_bf = (unsigned short*)(ws);              // 1 MB
    unsigned short* e3bf = (unsigned short*)(ws + 1048576);    // 2 MB
    float* hb            = (float*)(ws + 3145728);             // 2 MB
    unsigned short* w4p  = (unsigned short*)(ws + 5242880);    // 4.25 MB
    float* agg           = (float*)(ws + 9699328);             // 2 MB
    unsigned short* l1bf = (unsigned short*)(ws + 9699328);    // 2 MB (ALIASES agg: dead before memset)
    float* cnt           = (float*)(ws + 11796480);            // 16 KB
    unsigned short* w2p  = (unsigned short*)(ws + 11812864);   // 69632 B
    unsigned short* w3p  = (unsigned short*)(ws + 11882496);   // 67584 B

    pre_kernel<<<452, 256, 0, stream>>>(
        x, p1w, p1b, p2w, p2b, b4, h_bf, hb,
        ea, w1, b1, w4, w4p, w2, w2p, w3, w3p, l1bf);
    edge23_kernel<<<256, 256, 0, stream>>>(l1bf, b2, b3, w2p, w3p, e3bf);
    // agg/cnt cleared AFTER edge23 (l1bf shares agg's workspace region)
    hipMemsetAsync(agg, 0, (size_t)N_NODES * 128 * 4 + (size_t)N_NODES * 4, stream);
    nnconv_kernel<<<512, 256, 0, stream>>>(e3bf, h_bf, w4p, hb, ei, agg, cnt);
    pool_kernel<<<N_GRAPHS, 128, 0, stream>>>(agg, cnt, batch, out);
}